// Round 1
// 764.725 us; speedup vs baseline: 1.0293x; 1.0293x over previous
//
#include <hip/hip_runtime.h>
#include <math.h>

#define B_ 16
#define S_ 4096
#define H_ 1024
#define Q_ 1024
#define K_ 2048

typedef float f4 __attribute__((ext_vector_type(4)));

__device__ __forceinline__ float fast_tanh(float x) {
    // tanh(x) = 1 - 2/(exp(2x)+1); exact at both saturations
    float e = __expf(2.0f * x);
    float r = __builtin_amdgcn_rcpf(e + 1.0f);   // v_rcp_f32, ~1 ulp
    return 1.0f - 2.0f * r;
}

__device__ __forceinline__ float wave_reduce_sum(float v) {
#pragma unroll
    for (int off = 32; off > 0; off >>= 1)
        v += __shfl_xor(v, off, 64);
    return v;
}

// ---------------- kernel 1: q[b,h] = sum_q query[b,q] * Wq[h,q] ----------------
// 16 (b,h) pairs per block; query row cached in registers per wave (4 rows reuse)
__global__ __launch_bounds__(256) void qproj_kernel(const float* __restrict__ query,
                                                    const float* __restrict__ Wq,
                                                    float* __restrict__ qws) {
    int lane = threadIdx.x & 63;
    int wid  = threadIdx.x >> 6;
    int gbase = blockIdx.x * 16;         // all 16 pairs share the same b (H_%16==0)
    int b = gbase >> 10;                 // H_=1024
    const f4* qrow = (const f4*)(query + (size_t)b * Q_);
    f4 qv[4];
#pragma unroll
    for (int m = 0; m < 4; ++m) qv[m] = qrow[m * 64 + lane];
#pragma unroll
    for (int t = 0; t < 4; ++t) {
        int g = gbase + wid * 4 + t;
        const f4* wrow = (const f4*)(Wq + (size_t)(g & 1023) * Q_);
        float acc = 0.f;
#pragma unroll
        for (int m = 0; m < 4; ++m) {
            f4 w = wrow[m * 64 + lane];
            acc += w.x * qv[m].x + w.y * qv[m].y + w.z * qv[m].z + w.w * qv[m].w;
        }
        acc = wave_reduce_sum(acc);
        if (lane == 0) qws[g] = acc;
    }
}

// ---------------- kernel 2: scores[b,s] = sum_h tanh(q[b,h]+pk[b,s,h]) * we[h] ----------------
// 16 rows per block; q[b]/we cached in registers (loaded once per block instead of per row);
// masked rows skipped at wave granularity (pk row never fetched); pk is single-use -> nt loads
__global__ __launch_bounds__(256) void scores_kernel(const float* __restrict__ pk,
                                                     const float* __restrict__ qws,
                                                     const float* __restrict__ we,
                                                     const int* __restrict__ mask,
                                                     float* __restrict__ scores) {
    int lane = threadIdx.x & 63;
    int wid  = threadIdx.x >> 6;
    int rowbase = blockIdx.x * 16;       // all 16 rows share the same b (S_%16==0)
    int b = rowbase >> 12;               // S_=4096
    const f4* qrow = (const f4*)(qws + (size_t)b * H_);
    const f4* wrow = (const f4*)we;
    f4 qv[4], wv[4];
#pragma unroll
    for (int m = 0; m < 4; ++m) {
        qv[m] = qrow[m * 64 + lane];
        wv[m] = wrow[m * 64 + lane];
    }
    int mk[4];
#pragma unroll
    for (int t = 0; t < 4; ++t) mk[t] = mask[rowbase + wid * 4 + t];
#pragma unroll
    for (int t = 0; t < 4; ++t) {
        if (mk[t] == 0) continue;        // wave-uniform: whole wave owns the row
        int row = rowbase + wid * 4 + t;
        const f4* prow = (const f4*)(pk + (size_t)row * H_);
        float acc = 0.f;
#pragma unroll
        for (int m = 0; m < 4; ++m) {
            f4 p = __builtin_nontemporal_load(&prow[m * 64 + lane]);
            f4 s = qv[m] + p;
            acc += fast_tanh(s.x) * wv[m].x;
            acc += fast_tanh(s.y) * wv[m].y;
            acc += fast_tanh(s.z) * wv[m].z;
            acc += fast_tanh(s.w) * wv[m].w;
        }
        acc = wave_reduce_sum(acc);
        if (lane == 0) scores[row] = acc;
    }
}

// ---------------- kernel 3: masked softmax + ordered compaction; one block per b ----------------
// 1024 threads, 4 s each (float4 loads); 2 barriers total (shfl-scan instead of Hillis-Steele)
__global__ __launch_bounds__(1024) void softmax_kernel(const float* __restrict__ scores,
                                                       const int* __restrict__ mask,
                                                       float* __restrict__ alphas,
                                                       int* __restrict__ cidx,
                                                       float* __restrict__ calpha,
                                                       int* __restrict__ count) {
    int b = blockIdx.x;
    int tid = threadIdx.x;
    int lane = tid & 63;
    int wid  = tid >> 6;                 // 16 waves
    __shared__ float redmax[16];
    __shared__ float redsum[16];
    __shared__ int   wsum[16];
    int base = b * S_ + tid * 4;
    f4   sc = *(const f4*)(scores + base);
    int4 mm = *(const int4*)(mask + base);
    float v0 = mm.x ? sc.x : -INFINITY;
    float v1 = mm.y ? sc.y : -INFINITY;
    float v2 = mm.z ? sc.z : -INFINITY;
    float v3 = mm.w ? sc.w : -INFINITY;
    float lmax = fmaxf(fmaxf(v0, v1), fmaxf(v2, v3));
#pragma unroll
    for (int off = 32; off > 0; off >>= 1)
        lmax = fmaxf(lmax, __shfl_xor(lmax, off, 64));
    if (lane == 0) redmax[wid] = lmax;
    __syncthreads();
    float mx = redmax[0];
#pragma unroll
    for (int w = 1; w < 16; ++w) mx = fmaxf(mx, redmax[w]);
    float e0 = mm.x ? __expf(v0 - mx) : 0.f;
    float e1 = mm.y ? __expf(v1 - mx) : 0.f;
    float e2 = mm.z ? __expf(v2 - mx) : 0.f;
    float e3 = mm.w ? __expf(v3 - mx) : 0.f;
    float lsum = (e0 + e1) + (e2 + e3);
    lsum = wave_reduce_sum(lsum);
    if (lane == 0) redsum[wid] = lsum;
    int myc = (mm.x != 0) + (mm.y != 0) + (mm.z != 0) + (mm.w != 0);
    // wave-level inclusive scan of active counts
    int x = myc;
#pragma unroll
    for (int off = 1; off < 64; off <<= 1) {
        int y = __shfl_up(x, off, 64);
        if (lane >= off) x += y;
    }
    if (lane == 63) wsum[wid] = x;
    __syncthreads();
    float total = 0.f;
#pragma unroll
    for (int w = 0; w < 16; ++w) total += redsum[w];
    int woff = 0;
    for (int w = 0; w < wid; ++w) woff += wsum[w];
    int pos = woff + x - myc;            // exclusive prefix across the block
    if (tid == 1023) count[b] = woff + x;
    float rinv = 1.0f / total;
    float a0 = e0 * rinv, a1 = e1 * rinv, a2 = e2 * rinv, a3 = e3 * rinv;
    f4 av; av.x = a0; av.y = a1; av.z = a2; av.w = a3;
    *(f4*)(alphas + base) = av;          // exact 0 at masked positions, matches reference
    int sbase = b * S_;
    int s0 = tid * 4;
    if (mm.x) { cidx[sbase + pos] = s0 + 0; calpha[sbase + pos] = a0; pos++; }
    if (mm.y) { cidx[sbase + pos] = s0 + 1; calpha[sbase + pos] = a1; pos++; }
    if (mm.z) { cidx[sbase + pos] = s0 + 2; calpha[sbase + pos] = a2; pos++; }
    if (mm.w) { cidx[sbase + pos] = s0 + 3; calpha[sbase + pos] = a3; pos++; }
}

// ---------------- kernel 4: partial context over compacted active rows ----------------
// grid (schunks, K_/1024, B_); block 256; thread owns a float4 of k
// value rows are single-use -> nt loads; unroll 8 for memory-level parallelism
__global__ __launch_bounds__(256) void context_partial_kernel(const float* __restrict__ value,
                                                              const float* __restrict__ calpha,
                                                              const int* __restrict__ cidx,
                                                              const int* __restrict__ count,
                                                              float* __restrict__ partial,
                                                              int schunks, int Lmax) {
    extern __shared__ float sh[];
    float* la = sh;
    int*   li = (int*)(sh + Lmax);
    int c  = blockIdx.x;
    int kt = blockIdx.y;
    int b  = blockIdx.z;
    int tid = threadIdx.x;
    int cnt = count[b];
    int L = (cnt + schunks - 1) / schunks;
    int j0 = c * L;
    int j1 = j0 + L; if (j1 > cnt) j1 = cnt;
    int n = j1 - j0; if (n < 0) n = 0;
    for (int i = tid; i < n; i += 256) {
        la[i] = calpha[b * S_ + j0 + i];
        li[i] = cidx[b * S_ + j0 + i];
    }
    __syncthreads();
    const float* vbase = value + (size_t)b * S_ * K_ + kt * 1024;
    f4 acc = {0.f, 0.f, 0.f, 0.f};
#pragma unroll 8
    for (int i = 0; i < n; ++i) {
        float a = la[i];
        int   s = li[i];
        f4 vv = __builtin_nontemporal_load((const f4*)(vbase + (size_t)s * K_) + tid);
        acc.x = fmaf(a, vv.x, acc.x);
        acc.y = fmaf(a, vv.y, acc.y);
        acc.z = fmaf(a, vv.z, acc.z);
        acc.w = fmaf(a, vv.w, acc.w);
    }
    f4* pout = (f4*)(partial + ((size_t)(b * schunks + c)) * K_ + kt * 1024) + tid;
    *pout = acc;   // unconditional: partial buffer is poisoned, must be defined
}

// ---------------- kernel 5: reduce partials into context ----------------
__global__ __launch_bounds__(256) void context_reduce_kernel(const float* __restrict__ partial,
                                                             float* __restrict__ ctx,
                                                             int schunks) {
    int idx = blockIdx.x * 256 + threadIdx.x;   // over B_*K_/4
    int b  = idx >> 9;                          // K_/4 = 512
    int k4 = idx & 511;
    f4 acc = {0.f, 0.f, 0.f, 0.f};
    for (int c = 0; c < schunks; ++c) {
        f4 p = *((const f4*)(partial + ((size_t)(b * schunks + c)) * K_) + k4);
        acc.x += p.x; acc.y += p.y; acc.z += p.z; acc.w += p.w;
    }
    *((f4*)ctx + idx) = acc;
}

extern "C" void kernel_launch(void* const* d_in, const int* in_sizes, int n_in,
                              void* d_out, int out_size, void* d_ws, size_t ws_size,
                              hipStream_t stream) {
    const int*   mask     = (const int*)d_in[0];
    const float* query    = (const float*)d_in[1];
    const float* proj_key = (const float*)d_in[2];
    const float* value    = (const float*)d_in[3];
    const float* Wq       = (const float*)d_in[4];
    const float* w_energy = (const float*)d_in[5];

    float* out    = (float*)d_out;
    float* ctx    = out;            // B*1*K
    float* alphas = out + B_ * K_;  // B*1*S

    float* ws      = (float*)d_ws;
    float* qws     = ws;                                   // B*H
    float* scores  = qws + B_ * H_;                        // B*S
    float* calpha  = scores + B_ * S_;                     // B*S
    int*   cidx    = (int*)(calpha + B_ * S_);             // B*S
    int*   count   = cidx + B_ * S_;                       // B
    float* partial = (float*)(count + 64);                 // schunks*B*K

    size_t used_head = (size_t)(B_ * H_ + 3 * B_ * S_ + 64);
    size_t avail = ws_size / 4;
    avail = (avail > used_head) ? (avail - used_head) : 0;
    int schunks = 64;
    while (schunks > 1 && (size_t)schunks * B_ * K_ > avail) schunks >>= 1;
    int Lmax = (S_ + schunks - 1) / schunks;

    qproj_kernel<<<(B_ * H_) / 16, 256, 0, stream>>>(query, Wq, qws);
    scores_kernel<<<(B_ * S_) / 16, 256, 0, stream>>>(proj_key, qws, w_energy, mask, scores);
    softmax_kernel<<<B_, 1024, 0, stream>>>(scores, mask, alphas, cidx, calpha, count);
    dim3 g4(schunks, K_ / 1024, B_);
    size_t shbytes = (size_t)Lmax * (sizeof(float) + sizeof(int));
    context_partial_kernel<<<g4, 256, shbytes, stream>>>(value, calpha, cidx, count, partial,
                                                         schunks, Lmax);
    context_reduce_kernel<<<(B_ * K_) / 4 / 256, 256, 0, stream>>>(partial, ctx, schunks);
}